// Round 5
// baseline (142.955 us; speedup 1.0000x reference)
//
#include <hip/hip_runtime.h>

// Hawkes log-likelihood, D=1024 dims, M=32768 events, BETA=1.
//
// lam_i = mu[d_i] + sum_{j<i} alpha[d_i,d_j] * exp(t_j - t_i).
// Chunk events into NC=512 chunks of C=64:
//   cross-chunk: exp(t_c0 - t_i) * dot(alpha[d_i,:], S_c)
//   in-chunk:    one lane-parallel predicated gather step (C == wave size)
// S_c via TWO-LEVEL dimension-parallel scan; level-1 histogram+scan fused in
// LDS (k_fused); level-2 fixup S = Sl + Sg*cumdec fused into k_main's S load.
// Compensator via algebra: sum_j colsum[j]*contrib[j] = sum_r dot(alpha[r,:],
// contrib)  -> contrib histogram first (k_hist), dot folded into k_prep.
//
// R2 lesson: same-cacheline global atomics serialize (~15ns each) — ZERO
// global atomics anywhere. R4 lesson: pipeline of many small dispatches
// dominates — consolidated to 6 kernels, no multi-kernel global round-trips.
//
// ws floats: alpha[D*D] | Sl[NC*D] | mu[D] | contrib[D] | compP[260] |
//            llp[NB] | A[NG*D] | Sg[NG*D] | cumdec[NC]   (~6.3 MB)

#define D 1024
#define M 32768
#define C 64
#define NC (M / C)   /* 512 */
#define NB (NC * 4)  /* k_main blocks: 2048 */
#define NG 16        /* scan groups */
#define GC (NC / NG) /* 32 chunks per group */
#define TMAXV 1000.0f
#define EPSMU 1e-6f
#define EPSLOG 1e-8f

__device__ __forceinline__ float softplus(float x) {
    return (x > 0.0f) ? (x + log1pf(__expf(-x))) : log1pf(__expf(x));
}

// contrib[j] = sum_{i: d_i=j} (1 - exp(t_i - T)).  One block, LDS histogram.
__global__ void k_hist(const float* __restrict__ t_ev, const int* __restrict__ marks,
                       float* __restrict__ contrib) {
    __shared__ float h[D];
    int t = threadIdx.x;
    h[t] = 0.0f;
    __syncthreads();
#pragma unroll
    for (int it = 0; it < 32; ++it) {
        int i = it * 1024 + t;
        float w = 1.0f - __expf(t_ev[i] - TMAXV);
        atomicAdd(&h[marks[i]], w);  // LDS atomic: cheap
    }
    __syncthreads();
    contrib[t] = h[t];
}

// blocks 0..255: softplus(alpha) tile (4 rows x 1024 cols) + per-block
// compensator partial dot(alpha rows, contrib). block 256: mu.
__global__ void k_prep(const float* __restrict__ log_alpha, const float* __restrict__ log_mu,
                       const float* __restrict__ contrib, float* __restrict__ alpha,
                       float* __restrict__ mu, float* __restrict__ compP) {
    __shared__ float red[4];
    int t = threadIdx.x;
    int b = blockIdx.x;
    if (b < 256) {
        int r0 = b * 4;
        float cv[4];
#pragma unroll
        for (int q = 0; q < 4; ++q) cv[q] = contrib[t + 256 * q];
        float cp = 0.0f;
        for (int r = 0; r < 4; ++r) {
            size_t base = (size_t)(r0 + r) * D;
#pragma unroll
            for (int q = 0; q < 4; ++q) {
                int col = t + 256 * q;
                float a = softplus(log_alpha[base + col]);
                alpha[base + col] = a;
                cp += a * cv[q];
            }
        }
#pragma unroll
        for (int off = 32; off > 0; off >>= 1) cp += __shfl_xor(cp, off);
        int wave = t >> 6, lane = t & 63;
        if (lane == 0) red[wave] = cp;
        __syncthreads();
        if (t == 0) compP[b] = red[0] + red[1] + red[2] + red[3];
    } else {
#pragma unroll
        for (int q = 0; q < 4; ++q) {
            int k = t + 256 * q;
            mu[k] = softplus(log_mu[k]) + EPSMU;
        }
        if (t == 0) compP[256] = 0.0f;
    }
}

// Fused level-1: per-chunk histograms built in LDS, scanned in LDS.
// 64 blocks = 16 groups x 4 dim-slices of 256. Writes local prefix Sl and
// group aggregate A. Lh referenced at next chunk's start time.
__global__ void k_fused(const float* __restrict__ t_ev, const int* __restrict__ marks,
                        float* __restrict__ Sl, float* __restrict__ A) {
    __shared__ float Lh[GC * 256];  // 32 KB
    __shared__ float dec[GC];
    __shared__ float tns[GC];
    int g = blockIdx.x >> 2, db = blockIdx.x & 3;
    int t = threadIdx.x;
#pragma unroll
    for (int q = 0; q < GC; ++q) Lh[q * 256 + t] = 0.0f;
    if (t < GC) {
        int gc = g * GC + t;
        float tn = (gc + 1 < NC) ? t_ev[(gc + 1) * C] : t_ev[M - 1];
        tns[t] = tn;
        dec[t] = (gc + 1 < NC) ? __expf(t_ev[gc * C] - tn) : 1.0f;
    }
    __syncthreads();
    int base = g * (GC * C);  // 2048 events per group
#pragma unroll
    for (int it = 0; it < 8; ++it) {
        int e = it * 256 + t;
        float te = t_ev[base + e];
        int m = marks[base + e];
        int lc = e >> 6;
        int ml = m - db * 256;
        if ((unsigned)ml < 256u) atomicAdd(&Lh[lc * 256 + ml], __expf(te - tns[lc]));
    }
    __syncthreads();
    int k = db * 256 + t;
    float S = 0.0f;
    for (int lc = 0; lc < GC; ++lc) {
        Sl[(size_t)(g * GC + lc) * D + k] = S;
        S = S * dec[lc] + Lh[lc * 256 + t];
    }
    A[(size_t)g * D + k] = S;
}

// Level-2 scan over the 16 group aggregates + per-chunk scalar cumdec.
__global__ void k_scanB(const float* __restrict__ t_ev, const float* __restrict__ A,
                        float* __restrict__ Sg, float* __restrict__ cumdec) {
    __shared__ float dec[NC];
    __shared__ float P[NG];
    int t = threadIdx.x;
    if (t < NC)
        dec[t] = (t + 1 < NC) ? __expf(t_ev[t * C] - t_ev[(t + 1) * C]) : 1.0f;
    __syncthreads();
    if (t < NC) {
        int g = t >> 5, r = t & 31;
        float p = 1.0f;
        for (int j = 0; j < r; ++j) p *= dec[g * GC + j];
        cumdec[t] = p;
        if (r == GC - 1) P[g] = p * dec[t];
    }
    __syncthreads();
    float a[NG];
#pragma unroll
    for (int g2 = 0; g2 < NG; ++g2) a[g2] = A[(size_t)g2 * D + t];
    float S = 0.0f;
#pragma unroll
    for (int g2 = 0; g2 < NG; ++g2) {
        Sg[(size_t)g2 * D + t] = S;
        S = S * P[g2] + a[g2];
    }
}

// main: 4 blocks per chunk (16 events each), fused scan fixup.
// Per-block ll partials only (compensator handled by k_prep/k_final).
__launch_bounds__(256)
__global__ void k_main(const float* __restrict__ t_ev, const int* __restrict__ marks,
                       const float* __restrict__ alpha, const float* __restrict__ mu,
                       const float* __restrict__ Sl, const float* __restrict__ Sg,
                       const float* __restrict__ cumdec, float* __restrict__ llp) {
    __shared__ float S_lds[D];
    __shared__ float t_lds[C];
    __shared__ int d_lds[C];
    __shared__ float red[4];
    int t = threadIdx.x;
    int c = blockIdx.x >> 2, sub = blockIdx.x & 3;
    int g = c >> 5;
    float cd = cumdec[c];
#pragma unroll
    for (int q = 0; q < 4; ++q) {
        int k = t + 256 * q;
        S_lds[k] = Sl[(size_t)c * D + k] + Sg[(size_t)g * D + k] * cd;
    }
    if (t < C) {
        t_lds[t] = t_ev[c * C + t];
        d_lds[t] = marks[c * C + t];
    }
    __syncthreads();
    int wave = t >> 6, lane = t & 63;
    float t0 = t_lds[0];
    float ll_acc = 0.0f;
    for (int i = sub * 16 + wave; i < sub * 16 + 16; i += 4) {
        int row = d_lds[i];
        float ti = t_lds[i];
        float mu_r = mu[row];
        const float4* arow = (const float4*)(alpha + (size_t)row * D);
        const float4* srow = (const float4*)S_lds;
        float acc_dot = 0.0f;
#pragma unroll
        for (int u = 0; u < 4; ++u) {
            float4 a4 = arow[lane + 64 * u];
            float4 s4 = srow[lane + 64 * u];
            acc_dot += a4.x * s4.x + a4.y * s4.y + a4.z * s4.z + a4.w * s4.w;
        }
        float part = acc_dot * __expf(t0 - ti);
        if (lane < i) {
            part += alpha[(size_t)row * D + d_lds[lane]] * __expf(t_lds[lane] - ti);
        }
#pragma unroll
        for (int off = 32; off > 0; off >>= 1) part += __shfl_xor(part, off);
        if (lane == 0) ll_acc += __logf(mu_r + part + EPSLOG);
    }
    if (lane == 0) red[wave] = ll_acc;
    __syncthreads();
    if (t == 0) llp[blockIdx.x] = red[0] + red[1] + red[2] + red[3];
}

// final: out = sum(llp) - (T*sum(mu) + sum(compP)). 1 block, 1024 threads.
__global__ void k_final(const float* __restrict__ llp, const float* __restrict__ compP,
                        const float* __restrict__ mu, float* __restrict__ out) {
    __shared__ float r_ll[1024], r_cm[1024], r_mu[1024];
    int t = threadIdx.x;
    r_ll[t] = llp[t] + llp[t + 1024];
    r_cm[t] = (t < 257) ? compP[t] : 0.0f;
    r_mu[t] = mu[t];
    __syncthreads();
    for (int off = 512; off > 0; off >>= 1) {
        if (t < off) {
            r_ll[t] += r_ll[t + off];
            r_cm[t] += r_cm[t + off];
            r_mu[t] += r_mu[t + off];
        }
        __syncthreads();
    }
    if (t == 0) out[0] = r_ll[0] - (TMAXV * r_mu[0] + r_cm[0]);
}

extern "C" void kernel_launch(void* const* d_in, const int* in_sizes, int n_in,
                              void* d_out, int out_size, void* d_ws, size_t ws_size,
                              hipStream_t stream) {
    const float* t_ev = (const float*)d_in[0];
    const int* marks = (const int*)d_in[1];
    const float* log_mu = (const float*)d_in[2];
    const float* log_alpha = (const float*)d_in[3];
    float* out = (float*)d_out;

    float* w = (float*)d_ws;
    float* alpha = w;                       // D*D
    float* Sl = alpha + (size_t)D * D;      // NC*D
    float* mu = Sl + (size_t)NC * D;        // D
    float* contrib = mu + D;                // D
    float* compP = contrib + D;             // 260 (257 used)
    float* llp = compP + 260;               // NB
    float* A = llp + NB;                    // NG*D
    float* Sg = A + (size_t)NG * D;         // NG*D
    float* cumdec = Sg + (size_t)NG * D;    // NC

    k_hist<<<1, 1024, 0, stream>>>(t_ev, marks, contrib);
    k_prep<<<257, 256, 0, stream>>>(log_alpha, log_mu, contrib, alpha, mu, compP);
    k_fused<<<64, 256, 0, stream>>>(t_ev, marks, Sl, A);
    k_scanB<<<1, 1024, 0, stream>>>(t_ev, A, Sg, cumdec);
    k_main<<<NB, 256, 0, stream>>>(t_ev, marks, alpha, mu, Sl, Sg, cumdec, llp);
    k_final<<<1, 1024, 0, stream>>>(llp, compP, mu, out);
}